// Round 1
// baseline (157.950 us; speedup 1.0000x reference)
//
#include <hip/hip_runtime.h>
#include <math.h>

#define C 100
#define WAVES 4
#define ROWS_PER_PASS 64                          // per block per pass
#define PASSES 4
#define ROWS_PER_BLOCK (ROWS_PER_PASS * PASSES)   // 256
#define CHUNKS 25                                 // 1024-B chunks per pass (64*400/1024)
#define PASS_FLOATS (ROWS_PER_PASS * C)           // 6400 floats = 25600 B
#define INV_NORM 0.3989422804014327f              // 1/sqrt(2*pi), STD = 1
#define WFAR     0.67102943f                      // exp(-inv_norm) = lim w(d)

// quad (4-lane) sum via DPP quad_perm — VALU only, no DS pipe
__device__ __forceinline__ float quad_sum(float x) {
    x += __int_as_float(__builtin_amdgcn_update_dpp(
            0, __float_as_int(x), 0xB1, 0xF, 0xF, true));  // [1,0,3,2]
    x += __int_as_float(__builtin_amdgcn_update_dpp(
            0, __float_as_int(x), 0x4E, 0xF, 0xF, true));  // [2,3,0,1]
    return x;
}

// Math (verified in prior rounds): w(d) = exp(code(d)-inv_norm),
// code(d) = inv_norm*exp(-d^2/2); w'(d) = w(d)-wfar, zero for |d|>6.
//   csum = 100*wfar + sum_{valid d} w'(|d|)
//   dot  = wfar*rowsum + sum_{|d|<=6} w'(d) s_{mu+d}
//   dotc = sum_{valid d} w(|d|)*code(|d|)
//   kl_row = (dotc - dot)/csum - inv_norm - log(csum) + log(sum_j exp s_j)
//
// Data movement v2: global_load_lds DMA straight into a block-level LDS
// double buffer (25 x 1024-B chunks per 64-row pass — exact fit, no masked
// lanes, no VGPR staging, no ds_write). Counted s_waitcnt vmcnt(6) + raw
// s_barrier keeps the next pass's 25 DMA loads in flight across barriers
// (T3/T4 pattern) instead of __syncthreads' vmcnt(0) drain.
// LDS 51.2 KB/block -> 3 blocks/CU; each block sustains ~25 KB of DMA in
// flight, well above the ~9 KB/CU needed to saturate HBM.
__global__ __launch_bounds__(256, 3) void kl_main(
    const float* __restrict__ scores,
    const int*   __restrict__ labels,
    float* __restrict__ out, int n, float inv_n)
{
    __shared__ float buf[2][PASS_FLOATS];   // 2 x 25600 B
    __shared__ float wpart[WAVES];

    const int tid  = threadIdx.x;
    const int wave = tid >> 6, lane = tid & 63;
    const int r    = lane >> 2, sub  = lane & 3;   // quad r owns one row

    const int blockRow0 = blockIdx.x * ROWS_PER_BLOCK;
    const size_t totalBytes = (size_t)n * C * 4;

    // prefetch labels for all passes up-front (hides latency completely)
    int mu[PASSES];
    #pragma unroll
    for (int p = 0; p < PASSES; ++p) {
        int row = blockRow0 + p * ROWS_PER_PASS + wave * 16 + r;
        mu[p] = (row < n) ? labels[row] : 0;
    }

    float acc = 0.f;

    // stage pass p into buf[b]: wave w handles chunks {w, w+4, ...}
    // (wave0: 7 chunks, waves1-3: 6). Dest is wave-uniform; HW adds lane*16.
    auto stage = [&](int p, int b) {
        const size_t byteBase = (size_t)(blockRow0 + p * ROWS_PER_PASS) * (C * 4);
        #pragma unroll
        for (int k = 0; k < 7; ++k) {
            int c = wave + k * WAVES;
            if (c < CHUNKS) {
                size_t off = byteBase + (size_t)c * 1024;
                if (off + 1024 > totalBytes) off = totalBytes - 1024; // no-op when n%256==0
                const char* src = (const char*)scores + off + lane * 16;
                __builtin_amdgcn_global_load_lds(
                    (const __attribute__((address_space(1))) void*)src,
                    (__attribute__((address_space(3))) void*)&buf[b][c * 256],
                    16, 0, 0);
            }
        }
    };

    auto consume = [&](int p, int b) {
        const float* sp  = &buf[b][(wave * 16 + r) * C];
        const float* spl = sp + sub * 25;   // bank = (4r+25sub+i)%32: 2 lanes/bank, free
        float se = 0.f, rs = 0.f;
        #pragma unroll
        for (int i = 0; i < 25; ++i) {
            float s = spl[i];
            se += __expf(s);
            rs += s;
        }
        se = quad_sum(se);
        rs = quad_sum(rs);

        // 13-term window around mu, redundantly on all 4 lanes (broadcasts)
        const float WP[7] = {0.32897057f, 0.18369895f, 0.03722540f,
            0.00298049f, 8.9804e-5f, 9.9763e-7f, 4.0768e-9f};
        const float WC[7] = {0.39894228f, 0.20681926f, 0.03823936f,
            0.00298711f, 8.9816e-5f, 9.9765e-7f, 4.0768e-9f};
        float dotw = 0.f, csum = 100.f * WFAR, dotc = 0.f;
        const int m = mu[p];
        #pragma unroll
        for (int d = -6; d <= 6; ++d) {
            int idx  = m + d;
            bool ok  = (unsigned)idx < (unsigned)C;
            float s  = sp[min(max(idx, 0), C - 1)];
            int a    = d < 0 ? -d : d;               // compile-time
            float wv = ok ? WP[a] : 0.f;
            dotw  = fmaf(wv, s, dotw);
            csum += wv;
            dotc += ok ? WC[a] : 0.f;
        }

        int myrow = blockRow0 + p * ROWS_PER_PASS + wave * 16 + r;
        if (sub == 0 && myrow < n) {
            float dot = fmaf(WFAR, rs, dotw);
            acc += (dotc - dot) / csum - INV_NORM - __logf(csum) + __logf(se);
        }
    };

    // ---- pipeline: counted vmcnt, raw barriers (never drain to 0 mid-loop)
    // VM(6): each wave's own previous-pass chunks (<=7) complete; <=6 of the
    // next pass's may remain in flight. Barrier then makes them block-visible.
    #define VMBAR(N) do { asm volatile("s_waitcnt vmcnt(" #N ")" ::: "memory"); \
                          __builtin_amdgcn_s_barrier();                          \
                          asm volatile("" ::: "memory"); } while (0)
    #define BAR()    do { asm volatile("" ::: "memory");                         \
                          __builtin_amdgcn_s_barrier();                          \
                          asm volatile("" ::: "memory"); } while (0)

    stage(0, 0);
    stage(1, 1);

    VMBAR(6);          // pass 0 landed (pass 1 still in flight)
    consume(0, 0);
    BAR();             // all waves done reading buf0
    stage(2, 0);

    VMBAR(6);          // pass 1 landed (pass 2 in flight)
    consume(1, 1);
    BAR();             // all waves done reading buf1
    stage(3, 1);

    VMBAR(6);          // pass 2 landed (pass 3 in flight)
    consume(2, 0);

    VMBAR(0);          // drain: pass 3 landed
    consume(3, 1);

    #undef VMBAR
    #undef BAR

    // wave reduce (only sub==0 lanes nonzero) + block combine, 1 atomic/block
    #pragma unroll
    for (int off = 32; off > 0; off >>= 1)
        acc += __shfl_xor(acc, off, 64);
    if (lane == 0) wpart[wave] = acc;
    __syncthreads();
    if (tid == 0)
        atomicAdd(out, (wpart[0] + wpart[1] + wpart[2] + wpart[3]) * inv_n);
}

extern "C" void kernel_launch(void* const* d_in, const int* in_sizes, int n_in,
                              void* d_out, int out_size, void* d_ws, size_t ws_size,
                              hipStream_t stream)
{
    const float* scores = (const float*)d_in[0];
    const int*   labels = (const int*)d_in[1];
    float*       out    = (float*)d_out;

    int n = in_sizes[0] / C;   // 262144

    // d_out is poisoned (0xAA) before every timed launch — zero it first.
    hipMemsetAsync(d_out, 0, sizeof(float) * (size_t)out_size, stream);

    int blocks = (n + ROWS_PER_BLOCK - 1) / ROWS_PER_BLOCK;   // 1024
    kl_main<<<blocks, 256, 0, stream>>>(scores, labels, out, n, 1.0f / (float)n);
}